// Round 10
// baseline (918.713 us; speedup 1.0000x reference)
//
#include <hip/hip_runtime.h>
#include <hip/hip_bf16.h>
#include <math.h>

#define BATCH 32

typedef short bf16x8 __attribute__((ext_vector_type(8)));
typedef float f32x4 __attribute__((ext_vector_type(4)));

__device__ __forceinline__ float sigmoidf_(float x){ return 1.0f/(1.0f + __expf(-x)); }
__device__ __forceinline__ unsigned short f2bf(float x){
  unsigned u = __float_as_uint(x);
  unsigned r = (u + 0x7FFFu + ((u>>16)&1u)) >> 16;
  return (unsigned short)r;
}
__device__ __forceinline__ float sig2(float x){
  return __builtin_amdgcn_rcpf(1.0f + __builtin_amdgcn_exp2f(x * -1.44269504f));
}
__device__ __forceinline__ float tanh2(float x){
  return 1.0f - 2.0f*__builtin_amdgcn_rcpf(1.0f + __builtin_amdgcn_exp2f(x * 2.88539008f));
}
__device__ __forceinline__ f32x4 unpk4(uint2 p){
  f32x4 r;
  r[0] = __uint_as_float(p.x << 16);
  r[1] = __uint_as_float(p.x & 0xffff0000u);
  r[2] = __uint_as_float(p.y << 16);
  r[3] = __uint_as_float(p.y & 0xffff0000u);
  return r;
}
__device__ __forceinline__ bf16x8 pack8(float4 a, float4 b){
  bf16x8 f;
  f[0]=(short)f2bf(a.x); f[1]=(short)f2bf(a.y); f[2]=(short)f2bf(a.z); f[3]=(short)f2bf(a.w);
  f[4]=(short)f2bf(b.x); f[5]=(short)f2bf(b.y); f[6]=(short)f2bf(b.z); f[7]=(short)f2bf(b.w);
  return f;
}

// ---------------- K1 v3: MFMA streaming GEMM with LDS-bf16 x.
// Per block: convert x (32x1024 f32) once into 64KB LDS as [kblk 128][row 32][8] bf16;
// then wave w computes rows j0=blk*64+16w..+15 x 32 batches. W f32->bf16 in regs,
// double-buffered. Blocks 1000..1015: fb = sigmoid(x@W_inproj.T + b_inproj).
__global__ __launch_bounds__(256) void k1_emb(const float* __restrict__ x,
    const float* __restrict__ W_emb, const float* __restrict__ b_emb,
    const float* __restrict__ W_inp, const float* __restrict__ b_inp,
    float* __restrict__ ns, float* __restrict__ fb)
{
  __shared__ __align__(16) unsigned short xb[32768];   // 64 KB
  const int tid = threadIdx.x;
  for (int i = tid; i < 4096; i += 256){
    int row = i >> 7, kblk = i & 127;
    const float* src = x + row*1024 + kblk*8;
    float4 a = *(const float4*)src;
    float4 b = *(const float4*)(src+4);
    *(bf16x8*)&xb[(kblk*32 + row)*8] = pack8(a, b);
  }
  __syncthreads();
  const int w = tid >> 6, lane = tid & 63;
  const int nl = lane & 15, g = lane >> 4;
  const int blk = blockIdx.x;
  const bool isemb = (blk < 1000);
  const int j0 = (isemb ? blk : (blk - 1000))*64 + w*16;
  const int arow = j0 + nl;
  const float* wrow = isemb ? (W_emb + (size_t)arow*1024)
                            : (W_inp + (size_t)(arow > 999 ? 999 : arow)*1024);
  f32x4 D0, D1;
  #pragma unroll
  for (int q=0;q<4;q++){
    int jr = j0 + 4*g + q;
    float bb = isemb ? b_emb[jr] : b_inp[jr > 999 ? 999 : jr];
    D0[q] = bb; D1[q] = bb;
  }
  float4 wa[2][8];
  #pragma unroll
  for (int s=0;s<4;s++){
    const float* p = wrow + s*32 + 8*g;
    wa[0][2*s]   = *(const float4*)p;
    wa[0][2*s+1] = *(const float4*)(p+4);
  }
  for (int kc=0; kc<8; kc++){
    const int cur = kc & 1;
    if (kc < 7){
      #pragma unroll
      for (int s=0;s<4;s++){
        const float* p = wrow + (kc+1)*128 + s*32 + 8*g;
        wa[cur^1][2*s]   = *(const float4*)p;
        wa[cur^1][2*s+1] = *(const float4*)(p+4);
      }
    }
    #pragma unroll
    for (int s=0;s<4;s++){
      const int kblk = kc*16 + s*4 + g;
      bf16x8 A  = pack8(wa[cur][2*s], wa[cur][2*s+1]);
      bf16x8 B0 = *(const bf16x8*)&xb[(kblk*32 + nl)*8];
      bf16x8 B1 = *(const bf16x8*)&xb[(kblk*32 + nl + 16)*8];
      D0 = __builtin_amdgcn_mfma_f32_16x16x32_bf16(A, B0, D0, 0,0,0);
      D1 = __builtin_amdgcn_mfma_f32_16x16x32_bf16(A, B1, D1, 0,0,0);
    }
  }
  if (isemb){
    *(f32x4*)&ns[(size_t)nl*64000 + j0 + 4*g] = D0;
    *(f32x4*)&ns[(size_t)(nl+16)*64000 + j0 + 4*g] = D1;
  } else {
    #pragma unroll
    for (int q=0;q<4;q++){
      int jr = j0 + 4*g + q;
      if (jr < 1000){
        fb[nl*1000 + jr]      = sig2(D0[q]);
        fb[(nl+16)*1000 + jr] = sig2(D1[q]);
      }
    }
  }
}

// ---------------- K2: preh[rn][perm(j)] = bf16( ns[rn,:]@w_ih[j,:] + b_ih[j] + b_hh[j] )
__global__ __launch_bounds__(256) void k2_pre(const float* __restrict__ ns,
   const float* __restrict__ w_ih, const float* __restrict__ b_ih, const float* __restrict__ b_hh,
   unsigned short* __restrict__ preh)
{
  __shared__ __align__(16) float nsl[64*64];   // 16KB
  const int tid = threadIdx.x;
  const int j = tid;                 // original gate-row 0..255 (gate = j>>6, jl = j&63)
  const int rn0 = blockIdx.x * 64;
  const int pcol = (j & 63)*4 + (j >> 6);
  float wreg[64];
  const float* wr = w_ih + j*64;
  #pragma unroll
  for (int k=0;k<64;k+=4){
    float4 v = *(const float4*)&wr[k];
    wreg[k]=v.x; wreg[k+1]=v.y; wreg[k+2]=v.z; wreg[k+3]=v.w;
  }
  float bias = b_ih[j] + b_hh[j];
  const float4* src = (const float4*)(ns + (size_t)rn0*64);
  for (int i=tid; i<64*16; i+=256) ((float4*)nsl)[i] = src[i];
  __syncthreads();
  for (int r=0;r<64;r++){
    float a0=0,a1=0,a2=0,a3=0;
    #pragma unroll
    for (int k=0;k<64;k+=4){
      float4 nv = *(const float4*)&nsl[r*64+k];
      a0=fmaf(nv.x,wreg[k],a0);   a1=fmaf(nv.y,wreg[k+1],a1);
      a2=fmaf(nv.z,wreg[k+2],a2); a3=fmaf(nv.w,wreg[k+3],a3);
    }
    preh[(size_t)(rn0+r)*256 + pcol] = f2bf((a0+a1)+(a2+a3) + bias);
  }
}

// ---------------- K3: blocks 0..7 = MFMA LSTM (256 thr, 4 waves, 4 batches);
//                     blocks 8..132 = SDE+conv. MFMA pairs now independent (+add).
__global__ __launch_bounds__(256) void k3_lstm_sde(
  const unsigned short* __restrict__ preh, unsigned short* __restrict__ lstmT,
  const float* __restrict__ w_hh,
  const float* __restrict__ noise, const float* __restrict__ fb,
  const float* __restrict__ conv_w, const float* __restrict__ decay_p,
  float* __restrict__ S0, float* __restrict__ S1, float* __restrict__ S2)
{
  __shared__ __align__(16) unsigned char shraw[8192];
  const int tid = threadIdx.x;
  if (blockIdx.x < 8){
    unsigned short* hls = (unsigned short*)shraw;   // [2][4][80] bf16 = 640 shorts
    const int b0 = blockIdx.x * 4;
    const int w = tid >> 6;          // wave 0..3
    const int lane = tid & 63;
    const int nl = lane & 15;
    const int g  = lane >> 4;        // 0..3
    const int r  = nl & 3;           // batch-local row
    const f32x4 z4 = {0.f,0.f,0.f,0.f};
    for (int i = tid; i < 640; i += 256) hls[i] = 0;
    bf16x8 A[4][2];
    #pragma unroll
    for (int tt=0; tt<4; tt++){
      const int rt = 4*w + tt;
      const float* wsrc = w_hh + (size_t)((nl&3)*64 + 4*rt + (nl>>2))*64;
      #pragma unroll
      for (int kh=0; kh<2; kh++){
        bf16x8 f;
        #pragma unroll
        for (int i=0;i<8;i++) f[i] = (short)f2bf(wsrc[kh*32 + 8*g + i]);
        A[tt][kh] = f;
      }
    }
    const int jg = 16*w + 4*(nl>>2) + g;
    const int bat = b0 + r;
    const unsigned short* pp = preh + (size_t)bat*256000 + jg*4;
    uint2 P[4];
    #pragma unroll
    for (int s=0;s<4;s++) P[s] = *(const uint2*)(pp + (size_t)s*256);
    const int rdA = r*80 + (g ^ r)*8;
    const int wr = r*80 + ((jg>>3) ^ r)*8 + (jg & 7);
    unsigned short* lt = lstmT + ((size_t)bat*64 + jg)*1000;
    const bool s1 = (nl & 4) != 0, s2 = (nl & 8) != 0;
    float c = 0.f;
    unsigned ph[4];
    __syncthreads();
    int buf = 0;
    for (int tb=0; tb<1000; tb+=8){
      #pragma unroll
      for (int u=0;u<8;u++){
        bf16x8 B0 = *(const bf16x8*)&hls[buf*320 + rdA];
        bf16x8 B1 = *(const bf16x8*)&hls[buf*320 + rdA + 32];
        const int slot = u & 3;
        f32x4 Cp = unpk4(P[slot]);
        int tp = tb + u + 4; if (tp > 999) tp = 999;
        P[slot] = *(const uint2*)(pp + (size_t)tp*256);
        f32x4 D0 = __builtin_amdgcn_mfma_f32_16x16x32_bf16(A[0][0], B0, Cp, 0,0,0);
        f32x4 E0 = __builtin_amdgcn_mfma_f32_16x16x32_bf16(A[0][1], B1, z4, 0,0,0);
        f32x4 D1 = __builtin_amdgcn_mfma_f32_16x16x32_bf16(A[1][0], B0, Cp, 0,0,0);
        f32x4 E1 = __builtin_amdgcn_mfma_f32_16x16x32_bf16(A[1][1], B1, z4, 0,0,0);
        f32x4 D2 = __builtin_amdgcn_mfma_f32_16x16x32_bf16(A[2][0], B0, Cp, 0,0,0);
        f32x4 E2 = __builtin_amdgcn_mfma_f32_16x16x32_bf16(A[2][1], B1, z4, 0,0,0);
        f32x4 D3 = __builtin_amdgcn_mfma_f32_16x16x32_bf16(A[3][0], B0, Cp, 0,0,0);
        f32x4 E3 = __builtin_amdgcn_mfma_f32_16x16x32_bf16(A[3][1], B1, z4, 0,0,0);
        float g0 = s2 ? (s1 ? D3[0]+E3[0] : D2[0]+E2[0]) : (s1 ? D1[0]+E1[0] : D0[0]+E0[0]);
        float g1 = s2 ? (s1 ? D3[1]+E3[1] : D2[1]+E2[1]) : (s1 ? D1[1]+E1[1] : D0[1]+E0[1]);
        float g2 = s2 ? (s1 ? D3[2]+E3[2] : D2[2]+E2[2]) : (s1 ? D1[2]+E1[2] : D0[2]+E0[2]);
        float g3 = s2 ? (s1 ? D3[3]+E3[3] : D2[3]+E2[3]) : (s1 ? D1[3]+E1[3] : D0[3]+E0[3]);
        float iv = sig2(g0), fv = sig2(g1), gv = tanh2(g2), ov = sig2(g3);
        c = fv*c + iv*gv;
        float h = ov * tanh2(c);
        unsigned hb = f2bf(h);
        if (u & 1) ph[u>>1] |= hb << 16; else ph[u>>1] = hb;
        hls[(buf^1)*320 + wr] = (unsigned short)hb;
        asm volatile("s_waitcnt lgkmcnt(0)" ::: "memory");
        __builtin_amdgcn_s_barrier();
        asm volatile("" ::: "memory");
        buf ^= 1;
      }
      *(uint4*)(lt + tb) = make_uint4(ph[0], ph[1], ph[2], ph[3]);
    }
  } else {
    float* cw = (float*)shraw;        // 641*3 = 1923 floats
    for (int f = tid; f < 641*3; f += 256) cw[f] = conv_w[f];
    __syncthreads();
    int idx = (blockIdx.x - 8)*256 + tid;   // < 32000
    if (idx < 32000){
      int b = idx / 1000, n = idx - b*1000;
      float fcoef = fb[b*1000 + (n/100)];
      float dr = decay_p[0];
      const float dt = 1.0f/640.0f;
      float adec = 1.0f - dr*dt;
      float g = fcoef * sqrtf(dt);
      const float* nptr = noise + (size_t)idx * 640;
      float X=0.f, s0=0.f, s1=0.f, s2=0.f;
      for (int t0=0;t0<640;t0+=4){
        float4 nz = *(const float4*)&nptr[t0];
        float nv[4] = {nz.x, nz.y, nz.z, nz.w};
        #pragma unroll
        for (int u=0;u<4;u++){
          X = fmaf(adec, X, g*nv[u]);
          int t = t0 + u + 1;
          s0 = fmaf(cw[t*3+0], X, s0);
          s1 = fmaf(cw[t*3+1], X, s1);
          s2 = fmaf(cw[t*3+2], X, s2);
        }
      }
      S0[idx]=s0; S1[idx]=s1; S2[idx]=s2;
    }
  }
}

// ---------------- K4: qkv projection. lstm history is transposed bf16 [b][j][t].
__global__ __launch_bounds__(256) void k4_qkv(const unsigned short* __restrict__ lstmT,
  const float* __restrict__ w_in, const float* __restrict__ b_in,
  unsigned short* __restrict__ Qb, unsigned short* __restrict__ Kb, unsigned short* __restrict__ Vt)
{
  __shared__ __align__(16) float wl[192*64];   // 48KB
  __shared__ float bl[192];
  const int tid = threadIdx.x;
  for (int i=tid;i<3072;i+=256) ((float4*)wl)[i] = ((const float4*)w_in)[i];
  if (tid < 192) bl[tid] = b_in[tid];
  __syncthreads();
  const int rl = tid & 127, dh = tid >> 7;
  const int rn = blockIdx.x*128 + rl;
  const int b = rn >> 10, n = rn & 1023;
  const bool valid = (n < 1000);
  const int nc = valid ? n : 999;
  float row[64];
  #pragma unroll
  for (int k=0;k<64;k++){
    unsigned v = lstmT[((size_t)b*64 + k)*1000 + nc];
    row[k] = valid ? __uint_as_float(v << 16) : 0.f;
  }
  for (int dc=0; dc<12; dc++){
    const int d0 = dh*96 + dc*8;
    float acc[8];
    #pragma unroll
    for (int u=0;u<8;u++) acc[u] = bl[d0+u];
    #pragma unroll
    for (int k=0;k<64;k+=4){
      float4 rv = *(const float4*)&row[k];
      #pragma unroll
      for (int u=0;u<8;u++){
        float4 wv = *(const float4*)&wl[(d0+u)*64 + k];
        acc[u]=fmaf(rv.x,wv.x,acc[u]); acc[u]=fmaf(rv.y,wv.y,acc[u]);
        acc[u]=fmaf(rv.z,wv.z,acc[u]); acc[u]=fmaf(rv.w,wv.w,acc[u]);
      }
    }
    unsigned short pk[8];
    #pragma unroll
    for (int u=0;u<8;u++) pk[u] = valid ? f2bf(acc[u]) : (unsigned short)0;
    if (d0 + 8 <= 64){
      *(bf16x8*)&Qb[(size_t)rn*64 + d0] = *(bf16x8*)pk;
    } else if (d0 + 8 <= 128){
      *(bf16x8*)&Kb[(size_t)rn*64 + (d0-64)] = *(bf16x8*)pk;
    } else {
      int dv = d0 - 128;
      #pragma unroll
      for (int u=0;u<8;u++) Vt[((size_t)b*64 + dv+u)*1024 + n] = pk[u];
    }
  }
}

// ---------------- K5: attention (paired kk, exp2, folded snv)
__global__ __launch_bounds__(256) void k5_attn(
  const unsigned short* __restrict__ Qb, const unsigned short* __restrict__ Kb,
  const unsigned short* __restrict__ Vt,
  float* __restrict__ attn_w, float* __restrict__ ctx)
{
  const int b = blockIdx.x;
  const int qblk = blockIdx.y;
  const int wid = threadIdx.x >> 6;
  const int lane = threadIdx.x & 63;
  const int r = lane & 15, gq = lane >> 4;
  const int q = qblk*64 + wid*16 + r;
  const bool gok = (gq < 2);
  const float SC2 = 0.25f * 1.44269504f;
  const f32x4 z4 = {0.f,0.f,0.f,0.f};

  bf16x8 qf[4];
  #pragma unroll
  for (int h=0; h<4; h++){
    bf16x8 f = {};
    if (gok) f = *(const bf16x8*)&Qb[(((size_t)b*1024)+q)*64 + h*16 + 8*gq];
    qf[h] = f;
  }
  float snv[4];
  #pragma unroll
  for (int h=0; h<4; h++){
    float es = 0.f;
    for (int kk=0; kk<63; kk++){
      bf16x8 kf = {};
      if (gok) kf = *(const bf16x8*)&Kb[(((size_t)b*1024)+(kk*16+r))*64 + h*16 + 8*gq];
      f32x4 d = __builtin_amdgcn_mfma_f32_16x16x32_bf16(kf, qf[h], z4, 0,0,0);
      float e0=__builtin_amdgcn_exp2f(d[0]*SC2), e1=__builtin_amdgcn_exp2f(d[1]*SC2);
      float e2=__builtin_amdgcn_exp2f(d[2]*SC2), e3=__builtin_amdgcn_exp2f(d[3]*SC2);
      if (kk == 62 && !gok){ e0=0;e1=0;e2=0;e3=0; }
      es += (e0+e1)+(e2+e3);
    }
    es += __shfl_xor(es, 16);
    es += __shfl_xor(es, 32);
    snv[h] = 0.25f / es;
  }
  f32x4 cacc[4] = {};
  float* awrow = attn_w + (size_t)b*1000000;
  for (int kkp=0; kkp<31; kkp++){
    const int kk = kkp*2;
    f32x4 aacc0 = z4, aacc1 = z4;
    #pragma unroll
    for (int h=0; h<4; h++){
      bf16x8 kf0 = {}, kf1 = {};
      if (gok){
        kf0 = *(const bf16x8*)&Kb[(((size_t)b*1024)+(kk*16+r))*64 + h*16 + 8*gq];
        kf1 = *(const bf16x8*)&Kb[(((size_t)b*1024)+(kk*16+16+r))*64 + h*16 + 8*gq];
      }
      f32x4 d0 = __builtin_amdgcn_mfma_f32_16x16x32_bf16(kf0, qf[h], z4, 0,0,0);
      f32x4 d1 = __builtin_amdgcn_mfma_f32_16x16x32_bf16(kf1, qf[h], z4, 0,0,0);
      float p00=__builtin_amdgcn_exp2f(d0[0]*SC2)*snv[h], p01=__builtin_amdgcn_exp2f(d0[1]*SC2)*snv[h];
      float p02=__builtin_amdgcn_exp2f(d0[2]*SC2)*snv[h], p03=__builtin_amdgcn_exp2f(d0[3]*SC2)*snv[h];
      float p10=__builtin_amdgcn_exp2f(d1[0]*SC2)*snv[h], p11=__builtin_amdgcn_exp2f(d1[1]*SC2)*snv[h];
      float p12=__builtin_amdgcn_exp2f(d1[2]*SC2)*snv[h], p13=__builtin_amdgcn_exp2f(d1[3]*SC2)*snv[h];
      aacc0[0]+=p00; aacc0[1]+=p01; aacc0[2]+=p02; aacc0[3]+=p03;
      aacc1[0]+=p10; aacc1[1]+=p11; aacc1[2]+=p12; aacc1[3]+=p13;
      const int slo = (r + 32*gq) & 63;
      const int shi = (slo + 16) & 63;
      {
        unsigned pa = (unsigned)f2bf(p00) | ((unsigned)f2bf(p01) << 16);
        unsigned pb = (unsigned)f2bf(p02) | ((unsigned)f2bf(p03) << 16);
        int b0_ = __shfl((int)pa, slo), b1_ = __shfl((int)pb, slo);
        int b2_ = __shfl((int)pa, shi), b3_ = __shfl((int)pb, shi);
        union { int i[4]; bf16x8 v; } pu;
        pu.i[0]=b0_; pu.i[1]=b1_; pu.i[2]=b2_; pu.i[3]=b3_;
        bf16x8 pfrag = pu.v;
        if (!gok) pfrag = (bf16x8){};
        bf16x8 vf = {};
        if (gok) vf = *(const bf16x8*)&Vt[(((size_t)b*64) + h*16 + r)*1024 + kk*16 + 8*gq];
        cacc[h] = __builtin_amdgcn_mfma_f32_16x16x32_bf16(vf, pfrag, cacc[h], 0,0,0);
      }
      {
        unsigned pa = (unsigned)f2bf(p10) | ((unsigned)f2bf(p11) << 16);
        unsigned pb = (unsigned)f2bf(p12) | ((unsigned)f2bf(p13) << 16);
        int b0_ = __shfl((int)pa, slo), b1_ = __shfl((int)pb, slo);
        int b2_ = __shfl((int)pa, shi), b3_ = __shfl((int)pb, shi);
        union { int i[4]; bf16x8 v; } pu;
        pu.i[0]=b0_; pu.i[1]=b1_; pu.i[2]=b2_; pu.i[3]=b3_;
        bf16x8 pfrag = pu.v;
        if (!gok) pfrag = (bf16x8){};
        bf16x8 vf = {};
        if (gok) vf = *(const bf16x8*)&Vt[(((size_t)b*64) + h*16 + r)*1024 + kk*16 + 16 + 8*gq];
        cacc[h] = __builtin_amdgcn_mfma_f32_16x16x32_bf16(vf, pfrag, cacc[h], 0,0,0);
      }
    }
    if (q < 1000){
      *(f32x4*)&awrow[(size_t)q*1000 + kk*16 + 4*gq] = aacc0;
      *(f32x4*)&awrow[(size_t)q*1000 + kk*16 + 16 + 4*gq] = aacc1;
    }
  }
  {
    const int kk = 62;
    f32x4 aacc = z4;
    #pragma unroll
    for (int h=0; h<4; h++){
      bf16x8 kf = {};
      if (gok) kf = *(const bf16x8*)&Kb[(((size_t)b*1024)+(kk*16+r))*64 + h*16 + 8*gq];
      f32x4 d = __builtin_amdgcn_mfma_f32_16x16x32_bf16(kf, qf[h], z4, 0,0,0);
      float p0=__builtin_amdgcn_exp2f(d[0]*SC2)*snv[h], p1=__builtin_amdgcn_exp2f(d[1]*SC2)*snv[h];
      float p2=__builtin_amdgcn_exp2f(d[2]*SC2)*snv[h], p3=__builtin_amdgcn_exp2f(d[3]*SC2)*snv[h];
      if (!gok){ p0=0;p1=0;p2=0;p3=0; }
      aacc[0]+=p0; aacc[1]+=p1; aacc[2]+=p2; aacc[3]+=p3;
      unsigned pa = (unsigned)f2bf(p0) | ((unsigned)f2bf(p1) << 16);
      unsigned pb = (unsigned)f2bf(p2) | ((unsigned)f2bf(p3) << 16);
      int slo = (r + 32*gq) & 63;
      int shi = (slo + 16) & 63;
      int b0_ = __shfl((int)pa, slo), b1_ = __shfl((int)pb, slo);
      int b2_ = __shfl((int)pa, shi), b3_ = __shfl((int)pb, shi);
      union { int i[4]; bf16x8 v; } pu;
      pu.i[0]=b0_; pu.i[1]=b1_; pu.i[2]=b2_; pu.i[3]=b3_;
      bf16x8 pfrag = pu.v;
      if (!gok) pfrag = (bf16x8){};
      bf16x8 vf = {};
      if (gok) vf = *(const bf16x8*)&Vt[(((size_t)b*64) + h*16 + r)*1024 + kk*16 + 8*gq];
      cacc[h] = __builtin_amdgcn_mfma_f32_16x16x32_bf16(vf, pfrag, cacc[h], 0,0,0);
    }
    if (q < 1000 && gok){
      *(f32x4*)&awrow[(size_t)q*1000 + kk*16 + 4*gq] = aacc;
    }
  }
  if (q < 1000){
    #pragma unroll
    for (int h=0; h<4; h++){
      f32x4 cv = cacc[h];
      cv[0]*=4.f; cv[1]*=4.f; cv[2]*=4.f; cv[3]*=4.f;
      *(f32x4*)&ctx[(((size_t)b*1024)+q)*64 + h*16 + 4*gq] = cv;
    }
  }
}

// ---------------- K67: blocks 0..255 = ctx partial column sums; 256..381 = agg
__global__ __launch_bounds__(256) void k67_psum_agg(const float* __restrict__ ctx,
  float* __restrict__ psum,
  const float* __restrict__ S0, const float* __restrict__ S1,
  const float* __restrict__ S2, const float* __restrict__ conv_b, float* __restrict__ agg)
{
  if (blockIdx.x < 256){
    __shared__ float part[256];
    const int blk = blockIdx.x;
    const int b = blk >> 3, seg = blk & 7;
    const int t = threadIdx.x, d = t & 63, sg = t >> 6;
    float s = 0.f;
    const int nend = seg*125 + 125;
    for (int n = seg*125 + sg; n < nend; n += 4)
      s += ctx[(((size_t)b*1024)+n)*64 + d];
    part[t] = s;
    __syncthreads();
    if (t < 64) psum[((size_t)b*8 + seg)*64 + t] = part[t] + part[64+t] + part[128+t] + part[192+t];
  } else {
    int i = (blockIdx.x - 256)*256 + threadIdx.x;
    if (i >= 32000) return;
    int n = i % 1000;
    float v = S1[i] + conv_b[0];
    if (n > 0)   v += S0[i-1];
    if (n < 999) v += S2[i+1];
    agg[i] = v;
  }
}

// ---------------- K68: blocks 0..31 = enn (psum -> relu -> W_fix); 32..159 = bicep
__global__ __launch_bounds__(256) void k68_enn_bicep(const float* __restrict__ psum,
  const float* __restrict__ w_out, const float* __restrict__ b_out,
  const float* __restrict__ W_fix, float* __restrict__ enn_out,
  const float* __restrict__ agg, const float* __restrict__ W_bout,
  const float* __restrict__ b_bout, float* __restrict__ bicep)
{
  if (blockIdx.x < 32){
    __shared__ __align__(16) float csum[64];
    __shared__ __align__(16) float epre[64];
    int b = blockIdx.x, t = threadIdx.x;
    if (t < 64){
      float a = 0;
      #pragma unroll
      for (int s2=0;s2<8;s2++) a += psum[((size_t)b*8 + s2)*64 + t];
      csum[t] = a;
    }
    __syncthreads();
    if (t < 64){
      const float* wr = w_out + t*64;
      float a = 0;
      #pragma unroll
      for (int k=0;k<64;k++) a = fmaf(csum[k], wr[k], a);
      epre[t] = fmaxf(a*(1.0f/1000.0f) + b_out[t], 0.0f);
    }
    __syncthreads();
    for (int m = t; m < 1024; m += 256){
      const float* fr = W_fix + m*64;
      float a = 0;
      #pragma unroll
      for (int k=0;k<64;k+=4){
        float4 e4 = *(const float4*)&epre[k];
        float4 f4 = *(const float4*)&fr[k];
        a=fmaf(e4.x,f4.x,a); a=fmaf(e4.y,f4.y,a); a=fmaf(e4.z,f4.z,a); a=fmaf(e4.w,f4.w,a);
      }
      enn_out[b*1024 + m] = a;
    }
  } else {
    int gt = (blockIdx.x - 32)*256 + threadIdx.x;
    int bb = gt & 31, m = gt >> 5;
    const float* wr = W_bout + (size_t)m*1000;
    const float* ar = agg + bb*1000;
    float a = 0;
    for (int n=0;n<1000;n+=4){
      float4 w4 = *(const float4*)&wr[n];
      float4 a4 = *(const float4*)&ar[n];
      a=fmaf(w4.x,a4.x,a); a=fmaf(w4.y,a4.y,a); a=fmaf(w4.z,a4.z,a); a=fmaf(w4.w,a4.w,a);
    }
    bicep[bb*1024 + m] = a + b_bout[m];
  }
}

// ---------------- K9: fused = [enn,bicep]@W_fuse.T + b_fuse
__global__ __launch_bounds__(256) void k9_fuse(const float* __restrict__ enn, const float* __restrict__ bic,
  const float* __restrict__ W_fuse, const float* __restrict__ b_fuse, float* __restrict__ fused)
{
  int gt = blockIdx.x*256 + threadIdx.x;
  int bb = gt & 31, m = gt >> 5;
  const float* er = enn + bb*1024;
  const float* br = bic + bb*1024;
  const float* wr = W_fuse + (size_t)m*2048;
  float a = 0;
  for (int jj=0;jj<1024;jj+=4){
    float4 e4 = *(const float4*)&er[jj];
    float4 w4 = *(const float4*)&wr[jj];
    a=fmaf(e4.x,w4.x,a); a=fmaf(e4.y,w4.y,a); a=fmaf(e4.z,w4.z,a); a=fmaf(e4.w,w4.w,a);
  }
  for (int jj=0;jj<1024;jj+=4){
    float4 b4 = *(const float4*)&br[jj];
    float4 w4 = *(const float4*)&wr[1024+jj];
    a=fmaf(b4.x,w4.x,a); a=fmaf(b4.y,w4.y,a); a=fmaf(b4.z,w4.z,a); a=fmaf(b4.w,w4.w,a);
  }
  fused[bb*1024 + m] = a + b_fuse[m];
}

// ---------------- K10: output = fused@W_proj.T + b_proj
__global__ __launch_bounds__(256) void k10_proj(const float* __restrict__ fused,
  const float* __restrict__ W_proj, const float* __restrict__ b_proj, float* __restrict__ outp)
{
  int gt = blockIdx.x*256 + threadIdx.x;
  int bb = gt & 31, m = gt >> 5;
  const float* fr = fused + bb*1024;
  const float* wr = W_proj + (size_t)m*1024;
  float a = 0;
  for (int jj=0;jj<1024;jj+=4){
    float4 f4 = *(const float4*)&fr[jj];
    float4 w4 = *(const float4*)&wr[jj];
    a=fmaf(f4.x,w4.x,a); a=fmaf(f4.y,w4.y,a); a=fmaf(f4.z,w4.z,a); a=fmaf(f4.w,w4.w,a);
  }
  outp[bb*1024 + m] = a + b_proj[m];
}

extern "C" void kernel_launch(void* const* d_in, const int* in_sizes, int n_in,
                              void* d_out, int out_size, void* d_ws, size_t ws_size,
                              hipStream_t stream)
{
  const float* x       = (const float*)d_in[0];
  const float* noise   = (const float*)d_in[1];
  const float* W_emb   = (const float*)d_in[2];
  const float* b_emb   = (const float*)d_in[3];
  const float* w_ih    = (const float*)d_in[4];
  const float* w_hh    = (const float*)d_in[5];
  const float* b_ih    = (const float*)d_in[6];
  const float* b_hh    = (const float*)d_in[7];
  const float* w_in    = (const float*)d_in[8];
  const float* b_in    = (const float*)d_in[9];
  const float* w_out   = (const float*)d_in[10];
  const float* b_out   = (const float*)d_in[11];
  const float* W_fix   = (const float*)d_in[12];
  const float* W_inp   = (const float*)d_in[13];
  const float* b_inp   = (const float*)d_in[14];
  const float* conv_w  = (const float*)d_in[15];
  const float* conv_b  = (const float*)d_in[16];
  const float* W_bout  = (const float*)d_in[17];
  const float* b_bout  = (const float*)d_in[18];
  const float* decay   = (const float*)d_in[19];
  const float* W_fuse  = (const float*)d_in[20];
  const float* b_fuse  = (const float*)d_in[21];
  const float* W_proj  = (const float*)d_in[22];
  const float* b_proj  = (const float*)d_in[23];

  float* out       = (float*)d_out;
  float* enn_out   = out + 32768;
  float* bicep_out = out + 65536;
  float* attn_out  = out + 98304;

  float* ws    = (float*)d_ws;
  float* fb    = ws;                    // 32000
  float* ns    = ws + 32000;            // 2,048,000 f32
  unsigned short* preh  = (unsigned short*)(ws + 2080000);   // 8,192,000 u16
  float* psum  = ws + 6200000;          // 16384
  unsigned short* lstmT = (unsigned short*)(ws + 10272000);  // 2,048,000 u16
  float* ctx   = ws + 12320000;         // 2,097,152
  float* S0    = ws + 14417152;         // 32000
  float* S1    = ws + 14449152;
  float* S2    = ws + 14481152;
  float* agg   = ws + 14513152;
  float* fused = ws + 14545152;         // 32768
  unsigned short* Qb = (unsigned short*)(ws + 14577920);  // 2,097,152 u16 each
  unsigned short* Kb = Qb + 2097152;
  unsigned short* Vt = Kb + 2097152;

  k1_emb<<<1016, 256, 0, stream>>>(x, W_emb, b_emb, W_inp, b_inp, ns, fb);
  k2_pre<<<500, 256, 0, stream>>>(ns, w_ih, b_ih, b_hh, preh);
  k3_lstm_sde<<<133, 256, 0, stream>>>(preh, lstmT, w_hh, noise, fb, conv_w, decay, S0, S1, S2);
  k4_qkv<<<256, 256, 0, stream>>>(lstmT, w_in, b_in, Qb, Kb, Vt);
  k5_attn<<<dim3(32,16), 256, 0, stream>>>(Qb, Kb, Vt, attn_out, ctx);
  k67_psum_agg<<<382, 256, 0, stream>>>(ctx, psum, S0, S1, S2, conv_b, agg);
  k68_enn_bicep<<<160, 256, 0, stream>>>(psum, w_out, b_out, W_fix, enn_out,
                                         agg, W_bout, b_bout, bicep_out);
  k9_fuse<<<128, 256, 0, stream>>>(enn_out, bicep_out, W_fuse, b_fuse, fused);
  k10_proj<<<128, 256, 0, stream>>>(fused, W_proj, b_proj, out);
}

// Round 11
// 824.347 us; speedup vs baseline: 1.1145x; 1.1145x over previous
//
#include <hip/hip_runtime.h>
#include <hip/hip_bf16.h>
#include <math.h>

#define BATCH 32

typedef short bf16x8 __attribute__((ext_vector_type(8)));
typedef float f32x4 __attribute__((ext_vector_type(4)));

__device__ __forceinline__ float sigmoidf_(float x){ return 1.0f/(1.0f + __expf(-x)); }
__device__ __forceinline__ unsigned short f2bf(float x){
  unsigned u = __float_as_uint(x);
  unsigned r = (u + 0x7FFFu + ((u>>16)&1u)) >> 16;
  return (unsigned short)r;
}
__device__ __forceinline__ float sig2(float x){
  return __builtin_amdgcn_rcpf(1.0f + __builtin_amdgcn_exp2f(x * -1.44269504f));
}
__device__ __forceinline__ float tanh2(float x){
  return 1.0f - 2.0f*__builtin_amdgcn_rcpf(1.0f + __builtin_amdgcn_exp2f(x * 2.88539008f));
}
__device__ __forceinline__ f32x4 unpk4(uint2 p){
  f32x4 r;
  r[0] = __uint_as_float(p.x << 16);
  r[1] = __uint_as_float(p.x & 0xffff0000u);
  r[2] = __uint_as_float(p.y << 16);
  r[3] = __uint_as_float(p.y & 0xffff0000u);
  return r;
}
__device__ __forceinline__ bf16x8 pack8(float4 a, float4 b){
  bf16x8 f;
  f[0]=(short)f2bf(a.x); f[1]=(short)f2bf(a.y); f[2]=(short)f2bf(a.z); f[3]=(short)f2bf(a.w);
  f[4]=(short)f2bf(b.x); f[5]=(short)f2bf(b.y); f[6]=(short)f2bf(b.z); f[7]=(short)f2bf(b.w);
  return f;
}

// ---------------- K1 v3: MFMA streaming GEMM with LDS-bf16 x (r10 form, kept).
__global__ __launch_bounds__(256) void k1_emb(const float* __restrict__ x,
    const float* __restrict__ W_emb, const float* __restrict__ b_emb,
    const float* __restrict__ W_inp, const float* __restrict__ b_inp,
    float* __restrict__ ns, float* __restrict__ fb)
{
  __shared__ __align__(16) unsigned short xb[32768];   // 64 KB
  const int tid = threadIdx.x;
  for (int i = tid; i < 4096; i += 256){
    int row = i >> 7, kblk = i & 127;
    const float* src = x + row*1024 + kblk*8;
    float4 a = *(const float4*)src;
    float4 b = *(const float4*)(src+4);
    *(bf16x8*)&xb[(kblk*32 + row)*8] = pack8(a, b);
  }
  __syncthreads();
  const int w = tid >> 6, lane = tid & 63;
  const int nl = lane & 15, g = lane >> 4;
  const int blk = blockIdx.x;
  const bool isemb = (blk < 1000);
  const int j0 = (isemb ? blk : (blk - 1000))*64 + w*16;
  const int arow = j0 + nl;
  const float* wrow = isemb ? (W_emb + (size_t)arow*1024)
                            : (W_inp + (size_t)(arow > 999 ? 999 : arow)*1024);
  f32x4 D0, D1;
  #pragma unroll
  for (int q=0;q<4;q++){
    int jr = j0 + 4*g + q;
    float bb = isemb ? b_emb[jr] : b_inp[jr > 999 ? 999 : jr];
    D0[q] = bb; D1[q] = bb;
  }
  float4 wa[2][8];
  #pragma unroll
  for (int s=0;s<4;s++){
    const float* p = wrow + s*32 + 8*g;
    wa[0][2*s]   = *(const float4*)p;
    wa[0][2*s+1] = *(const float4*)(p+4);
  }
  for (int kc=0; kc<8; kc++){
    const int cur = kc & 1;
    if (kc < 7){
      #pragma unroll
      for (int s=0;s<4;s++){
        const float* p = wrow + (kc+1)*128 + s*32 + 8*g;
        wa[cur^1][2*s]   = *(const float4*)p;
        wa[cur^1][2*s+1] = *(const float4*)(p+4);
      }
    }
    #pragma unroll
    for (int s=0;s<4;s++){
      const int kblk = kc*16 + s*4 + g;
      bf16x8 A  = pack8(wa[cur][2*s], wa[cur][2*s+1]);
      bf16x8 B0 = *(const bf16x8*)&xb[(kblk*32 + nl)*8];
      bf16x8 B1 = *(const bf16x8*)&xb[(kblk*32 + nl + 16)*8];
      D0 = __builtin_amdgcn_mfma_f32_16x16x32_bf16(A, B0, D0, 0,0,0);
      D1 = __builtin_amdgcn_mfma_f32_16x16x32_bf16(A, B1, D1, 0,0,0);
    }
  }
  if (isemb){
    *(f32x4*)&ns[(size_t)nl*64000 + j0 + 4*g] = D0;
    *(f32x4*)&ns[(size_t)(nl+16)*64000 + j0 + 4*g] = D1;
  } else {
    #pragma unroll
    for (int q=0;q<4;q++){
      int jr = j0 + 4*g + q;
      if (jr < 1000){
        fb[nl*1000 + jr]      = sig2(D0[q]);
        fb[(nl+16)*1000 + jr] = sig2(D1[q]);
      }
    }
  }
}

// ---------------- K2: preh[rn][perm(j)] = bf16( ns[rn,:]@w_ih[j,:] + b_ih[j] + b_hh[j] )
__global__ __launch_bounds__(256) void k2_pre(const float* __restrict__ ns,
   const float* __restrict__ w_ih, const float* __restrict__ b_ih, const float* __restrict__ b_hh,
   unsigned short* __restrict__ preh)
{
  __shared__ __align__(16) float nsl[64*64];   // 16KB
  const int tid = threadIdx.x;
  const int j = tid;                 // original gate-row 0..255 (gate = j>>6, jl = j&63)
  const int rn0 = blockIdx.x * 64;
  const int pcol = (j & 63)*4 + (j >> 6);
  float wreg[64];
  const float* wr = w_ih + j*64;
  #pragma unroll
  for (int k=0;k<64;k+=4){
    float4 v = *(const float4*)&wr[k];
    wreg[k]=v.x; wreg[k+1]=v.y; wreg[k+2]=v.z; wreg[k+3]=v.w;
  }
  float bias = b_ih[j] + b_hh[j];
  const float4* src = (const float4*)(ns + (size_t)rn0*64);
  for (int i=tid; i<64*16; i+=256) ((float4*)nsl)[i] = src[i];
  __syncthreads();
  for (int r=0;r<64;r++){
    float a0=0,a1=0,a2=0,a3=0;
    #pragma unroll
    for (int k=0;k<64;k+=4){
      float4 nv = *(const float4*)&nsl[r*64+k];
      a0=fmaf(nv.x,wreg[k],a0);   a1=fmaf(nv.y,wreg[k+1],a1);
      a2=fmaf(nv.z,wreg[k+2],a2); a3=fmaf(nv.w,wreg[k+3],a3);
    }
    preh[(size_t)(rn0+r)*256 + pcol] = f2bf((a0+a1)+(a2+a3) + bias);
  }
}

// ---------------- K3: REVERTED to r9 chained-MFMA form (measured 268us).
// blocks 0..7 = MFMA LSTM (256 thr, 4 waves, 4 batches); blocks 8..132 = SDE+conv.
__global__ __launch_bounds__(256) void k3_lstm_sde(
  const unsigned short* __restrict__ preh, unsigned short* __restrict__ lstmT,
  const float* __restrict__ w_hh,
  const float* __restrict__ noise, const float* __restrict__ fb,
  const float* __restrict__ conv_w, const float* __restrict__ decay_p,
  float* __restrict__ S0, float* __restrict__ S1, float* __restrict__ S2)
{
  __shared__ __align__(16) unsigned char shraw[8192];
  const int tid = threadIdx.x;
  if (blockIdx.x < 8){
    unsigned short* hls = (unsigned short*)shraw;   // [2][4][80] bf16 = 640 shorts
    const int b0 = blockIdx.x * 4;
    const int w = tid >> 6;          // wave 0..3
    const int lane = tid & 63;
    const int nl = lane & 15;
    const int g  = lane >> 4;        // 0..3
    const int r  = nl & 3;           // batch-local row
    for (int i = tid; i < 640; i += 256) hls[i] = 0;
    bf16x8 A[4][2];
    #pragma unroll
    for (int tt=0; tt<4; tt++){
      const int rt = 4*w + tt;
      const float* wsrc = w_hh + (size_t)((nl&3)*64 + 4*rt + (nl>>2))*64;
      #pragma unroll
      for (int kh=0; kh<2; kh++){
        bf16x8 f;
        #pragma unroll
        for (int i=0;i<8;i++) f[i] = (short)f2bf(wsrc[kh*32 + 8*g + i]);
        A[tt][kh] = f;
      }
    }
    const int jg = 16*w + 4*(nl>>2) + g;
    const int bat = b0 + r;
    const unsigned short* pp = preh + (size_t)bat*256000 + jg*4;
    uint2 P[4];
    #pragma unroll
    for (int s=0;s<4;s++) P[s] = *(const uint2*)(pp + (size_t)s*256);
    const int rdA = r*80 + (g ^ r)*8;
    const int wr = r*80 + ((jg>>3) ^ r)*8 + (jg & 7);
    unsigned short* lt = lstmT + ((size_t)bat*64 + jg)*1000;
    const bool s1 = (nl & 4) != 0, s2 = (nl & 8) != 0;
    float c = 0.f;
    unsigned ph[4];
    __syncthreads();
    int buf = 0;
    for (int tb=0; tb<1000; tb+=8){
      #pragma unroll
      for (int u=0;u<8;u++){
        bf16x8 B0 = *(const bf16x8*)&hls[buf*320 + rdA];
        bf16x8 B1 = *(const bf16x8*)&hls[buf*320 + rdA + 32];
        const int slot = u & 3;
        f32x4 Cp = unpk4(P[slot]);
        int tp = tb + u + 4; if (tp > 999) tp = 999;
        P[slot] = *(const uint2*)(pp + (size_t)tp*256);
        f32x4 D0 = __builtin_amdgcn_mfma_f32_16x16x32_bf16(A[0][0], B0, Cp, 0,0,0);
        D0 = __builtin_amdgcn_mfma_f32_16x16x32_bf16(A[0][1], B1, D0, 0,0,0);
        f32x4 D1 = __builtin_amdgcn_mfma_f32_16x16x32_bf16(A[1][0], B0, Cp, 0,0,0);
        D1 = __builtin_amdgcn_mfma_f32_16x16x32_bf16(A[1][1], B1, D1, 0,0,0);
        f32x4 D2 = __builtin_amdgcn_mfma_f32_16x16x32_bf16(A[2][0], B0, Cp, 0,0,0);
        D2 = __builtin_amdgcn_mfma_f32_16x16x32_bf16(A[2][1], B1, D2, 0,0,0);
        f32x4 D3 = __builtin_amdgcn_mfma_f32_16x16x32_bf16(A[3][0], B0, Cp, 0,0,0);
        D3 = __builtin_amdgcn_mfma_f32_16x16x32_bf16(A[3][1], B1, D3, 0,0,0);
        float g0 = s2 ? (s1 ? D3[0] : D2[0]) : (s1 ? D1[0] : D0[0]);
        float g1 = s2 ? (s1 ? D3[1] : D2[1]) : (s1 ? D1[1] : D0[1]);
        float g2 = s2 ? (s1 ? D3[2] : D2[2]) : (s1 ? D1[2] : D0[2]);
        float g3 = s2 ? (s1 ? D3[3] : D2[3]) : (s1 ? D1[3] : D0[3]);
        float iv = sig2(g0), fv = sig2(g1), gv = tanh2(g2), ov = sig2(g3);
        c = fv*c + iv*gv;
        float h = ov * tanh2(c);
        unsigned hb = f2bf(h);
        if (u & 1) ph[u>>1] |= hb << 16; else ph[u>>1] = hb;
        hls[(buf^1)*320 + wr] = (unsigned short)hb;
        asm volatile("s_waitcnt lgkmcnt(0)" ::: "memory");
        __builtin_amdgcn_s_barrier();
        asm volatile("" ::: "memory");
        buf ^= 1;
      }
      *(uint4*)(lt + tb) = make_uint4(ph[0], ph[1], ph[2], ph[3]);
    }
  } else {
    float* cw = (float*)shraw;        // 641*3 = 1923 floats
    for (int f = tid; f < 641*3; f += 256) cw[f] = conv_w[f];
    __syncthreads();
    int idx = (blockIdx.x - 8)*256 + tid;   // < 32000
    if (idx < 32000){
      int b = idx / 1000, n = idx - b*1000;
      float fcoef = fb[b*1000 + (n/100)];
      float dr = decay_p[0];
      const float dt = 1.0f/640.0f;
      float adec = 1.0f - dr*dt;
      float g = fcoef * sqrtf(dt);
      const float* nptr = noise + (size_t)idx * 640;
      float X=0.f, s0=0.f, s1=0.f, s2=0.f;
      for (int t0=0;t0<640;t0+=4){
        float4 nz = *(const float4*)&nptr[t0];
        float nv[4] = {nz.x, nz.y, nz.z, nz.w};
        #pragma unroll
        for (int u=0;u<4;u++){
          X = fmaf(adec, X, g*nv[u]);
          int t = t0 + u + 1;
          s0 = fmaf(cw[t*3+0], X, s0);
          s1 = fmaf(cw[t*3+1], X, s1);
          s2 = fmaf(cw[t*3+2], X, s2);
        }
      }
      S0[idx]=s0; S1[idx]=s1; S2[idx]=s2;
    }
  }
}

// ---------------- K4: qkv projection. lstm history is transposed bf16 [b][j][t].
__global__ __launch_bounds__(256) void k4_qkv(const unsigned short* __restrict__ lstmT,
  const float* __restrict__ w_in, const float* __restrict__ b_in,
  unsigned short* __restrict__ Qb, unsigned short* __restrict__ Kb, unsigned short* __restrict__ Vt)
{
  __shared__ __align__(16) float wl[192*64];   // 48KB
  __shared__ float bl[192];
  const int tid = threadIdx.x;
  for (int i=tid;i<3072;i+=256) ((float4*)wl)[i] = ((const float4*)w_in)[i];
  if (tid < 192) bl[tid] = b_in[tid];
  __syncthreads();
  const int rl = tid & 127, dh = tid >> 7;
  const int rn = blockIdx.x*128 + rl;
  const int b = rn >> 10, n = rn & 1023;
  const bool valid = (n < 1000);
  const int nc = valid ? n : 999;
  float row[64];
  #pragma unroll
  for (int k=0;k<64;k++){
    unsigned v = lstmT[((size_t)b*64 + k)*1000 + nc];
    row[k] = valid ? __uint_as_float(v << 16) : 0.f;
  }
  for (int dc=0; dc<12; dc++){
    const int d0 = dh*96 + dc*8;
    float acc[8];
    #pragma unroll
    for (int u=0;u<8;u++) acc[u] = bl[d0+u];
    #pragma unroll
    for (int k=0;k<64;k+=4){
      float4 rv = *(const float4*)&row[k];
      #pragma unroll
      for (int u=0;u<8;u++){
        float4 wv = *(const float4*)&wl[(d0+u)*64 + k];
        acc[u]=fmaf(rv.x,wv.x,acc[u]); acc[u]=fmaf(rv.y,wv.y,acc[u]);
        acc[u]=fmaf(rv.z,wv.z,acc[u]); acc[u]=fmaf(rv.w,wv.w,acc[u]);
      }
    }
    unsigned short pk[8];
    #pragma unroll
    for (int u=0;u<8;u++) pk[u] = valid ? f2bf(acc[u]) : (unsigned short)0;
    if (d0 + 8 <= 64){
      *(bf16x8*)&Qb[(size_t)rn*64 + d0] = *(bf16x8*)pk;
    } else if (d0 + 8 <= 128){
      *(bf16x8*)&Kb[(size_t)rn*64 + (d0-64)] = *(bf16x8*)pk;
    } else {
      int dv = d0 - 128;
      #pragma unroll
      for (int u=0;u<8;u++) Vt[((size_t)b*64 + dv+u)*1024 + n] = pk[u];
    }
  }
}

// ---------------- K5: REVERTED to r6 unpaired form (low VGPR pressure).
__global__ __launch_bounds__(256) void k5_attn(
  const unsigned short* __restrict__ Qb, const unsigned short* __restrict__ Kb,
  const unsigned short* __restrict__ Vt,
  float* __restrict__ attn_w, float* __restrict__ ctx)
{
  const int b = blockIdx.x;
  const int qblk = blockIdx.y;
  const int wid = threadIdx.x >> 6;
  const int lane = threadIdx.x & 63;
  const int r = lane & 15, gq = lane >> 4;
  const int q0 = qblk*64 + wid*16;
  const int q = q0 + r;
  const bool gok = (gq < 2);
  const float scale = 0.25f;
  const f32x4 z4 = {0.f,0.f,0.f,0.f};

  bf16x8 qf[4];
  #pragma unroll
  for (int h=0; h<4; h++){
    bf16x8 f = {};
    if (gok) f = *(const bf16x8*)&Qb[(((size_t)b*1024)+q)*64 + h*16 + 8*gq];
    qf[h] = f;
  }
  float sinv[4];
  #pragma unroll
  for (int h=0; h<4; h++){
    float es = 0.f;
    for (int kk=0; kk<63; kk++){
      bf16x8 kf = {};
      if (gok) kf = *(const bf16x8*)&Kb[(((size_t)b*1024)+(kk*16+r))*64 + h*16 + 8*gq];
      f32x4 d = __builtin_amdgcn_mfma_f32_16x16x32_bf16(kf, qf[h], z4, 0,0,0);
      float e0=__expf(d[0]*scale), e1=__expf(d[1]*scale), e2=__expf(d[2]*scale), e3=__expf(d[3]*scale);
      if (kk == 62 && !gok){ e0=0;e1=0;e2=0;e3=0; }
      es += (e0+e1)+(e2+e3);
    }
    es += __shfl_xor(es, 16);
    es += __shfl_xor(es, 32);
    sinv[h] = 1.0f / es;
  }
  f32x4 cacc[4] = {};
  float* awrow = attn_w + (size_t)b*1000000;
  for (int kk=0; kk<63; kk++){
    f32x4 aacc = z4;
    #pragma unroll
    for (int h=0; h<4; h++){
      bf16x8 kf = {};
      if (gok) kf = *(const bf16x8*)&Kb[(((size_t)b*1024)+(kk*16+r))*64 + h*16 + 8*gq];
      f32x4 d = __builtin_amdgcn_mfma_f32_16x16x32_bf16(kf, qf[h], z4, 0,0,0);
      float p0=__expf(d[0]*scale)*sinv[h], p1=__expf(d[1]*scale)*sinv[h];
      float p2=__expf(d[2]*scale)*sinv[h], p3=__expf(d[3]*scale)*sinv[h];
      if (kk == 62 && !gok){ p0=0;p1=0;p2=0;p3=0; }
      aacc[0] += 0.25f*p0; aacc[1] += 0.25f*p1; aacc[2] += 0.25f*p2; aacc[3] += 0.25f*p3;
      unsigned p01 = (unsigned)f2bf(p0) | ((unsigned)f2bf(p1) << 16);
      unsigned p23 = (unsigned)f2bf(p2) | ((unsigned)f2bf(p3) << 16);
      int slo = (r + 32*gq) & 63;
      int shi = (slo + 16) & 63;
      int b0 = __shfl((int)p01, slo), b1 = __shfl((int)p23, slo);
      int b2 = __shfl((int)p01, shi), b3 = __shfl((int)p23, shi);
      union { int i[4]; bf16x8 v; } pu;
      pu.i[0]=b0; pu.i[1]=b1; pu.i[2]=b2; pu.i[3]=b3;
      bf16x8 pfrag = pu.v;
      if (!gok) pfrag = (bf16x8){};
      bf16x8 vf = {};
      if (gok) vf = *(const bf16x8*)&Vt[(((size_t)b*64) + h*16 + r)*1024 + kk*16 + 8*gq];
      cacc[h] = __builtin_amdgcn_mfma_f32_16x16x32_bf16(vf, pfrag, cacc[h], 0,0,0);
    }
    int kbase = kk*16 + 4*gq;
    if (q < 1000 && !(kk==62 && !gok)){
      *(f32x4*)&awrow[(size_t)q*1000 + kbase] = aacc;
    }
  }
  if (q < 1000){
    #pragma unroll
    for (int h=0; h<4; h++){
      *(f32x4*)&ctx[(((size_t)b*1024)+q)*64 + h*16 + 4*gq] = cacc[h];
    }
  }
}

// ---------------- K67: blocks 0..255 = ctx partial column sums; 256..381 = agg
__global__ __launch_bounds__(256) void k67_psum_agg(const float* __restrict__ ctx,
  float* __restrict__ psum,
  const float* __restrict__ S0, const float* __restrict__ S1,
  const float* __restrict__ S2, const float* __restrict__ conv_b, float* __restrict__ agg)
{
  if (blockIdx.x < 256){
    __shared__ float part[256];
    const int blk = blockIdx.x;
    const int b = blk >> 3, seg = blk & 7;
    const int t = threadIdx.x, d = t & 63, sg = t >> 6;
    float s = 0.f;
    const int nend = seg*125 + 125;
    for (int n = seg*125 + sg; n < nend; n += 4)
      s += ctx[(((size_t)b*1024)+n)*64 + d];
    part[t] = s;
    __syncthreads();
    if (t < 64) psum[((size_t)b*8 + seg)*64 + t] = part[t] + part[64+t] + part[128+t] + part[192+t];
  } else {
    int i = (blockIdx.x - 256)*256 + threadIdx.x;
    if (i >= 32000) return;
    int n = i % 1000;
    float v = S1[i] + conv_b[0];
    if (n > 0)   v += S0[i-1];
    if (n < 999) v += S2[i+1];
    agg[i] = v;
  }
}

// ---------------- K68: blocks 0..31 = enn (psum -> relu -> W_fix); 32..159 = bicep
__global__ __launch_bounds__(256) void k68_enn_bicep(const float* __restrict__ psum,
  const float* __restrict__ w_out, const float* __restrict__ b_out,
  const float* __restrict__ W_fix, float* __restrict__ enn_out,
  const float* __restrict__ agg, const float* __restrict__ W_bout,
  const float* __restrict__ b_bout, float* __restrict__ bicep)
{
  if (blockIdx.x < 32){
    __shared__ __align__(16) float csum[64];
    __shared__ __align__(16) float epre[64];
    int b = blockIdx.x, t = threadIdx.x;
    if (t < 64){
      float a = 0;
      #pragma unroll
      for (int s2=0;s2<8;s2++) a += psum[((size_t)b*8 + s2)*64 + t];
      csum[t] = a;
    }
    __syncthreads();
    if (t < 64){
      const float* wr = w_out + t*64;
      float a = 0;
      #pragma unroll
      for (int k=0;k<64;k++) a = fmaf(csum[k], wr[k], a);
      epre[t] = fmaxf(a*(1.0f/1000.0f) + b_out[t], 0.0f);
    }
    __syncthreads();
    for (int m = t; m < 1024; m += 256){
      const float* fr = W_fix + m*64;
      float a = 0;
      #pragma unroll
      for (int k=0;k<64;k+=4){
        float4 e4 = *(const float4*)&epre[k];
        float4 f4 = *(const float4*)&fr[k];
        a=fmaf(e4.x,f4.x,a); a=fmaf(e4.y,f4.y,a); a=fmaf(e4.z,f4.z,a); a=fmaf(e4.w,f4.w,a);
      }
      enn_out[b*1024 + m] = a;
    }
  } else {
    int gt = (blockIdx.x - 32)*256 + threadIdx.x;
    int bb = gt & 31, m = gt >> 5;
    const float* wr = W_bout + (size_t)m*1000;
    const float* ar = agg + bb*1000;
    float a = 0;
    for (int n=0;n<1000;n+=4){
      float4 w4 = *(const float4*)&wr[n];
      float4 a4 = *(const float4*)&ar[n];
      a=fmaf(w4.x,a4.x,a); a=fmaf(w4.y,a4.y,a); a=fmaf(w4.z,a4.z,a); a=fmaf(w4.w,a4.w,a);
    }
    bicep[bb*1024 + m] = a + b_bout[m];
  }
}

// ---------------- K9: fused = [enn,bicep]@W_fuse.T + b_fuse
__global__ __launch_bounds__(256) void k9_fuse(const float* __restrict__ enn, const float* __restrict__ bic,
  const float* __restrict__ W_fuse, const float* __restrict__ b_fuse, float* __restrict__ fused)
{
  int gt = blockIdx.x*256 + threadIdx.x;
  int bb = gt & 31, m = gt >> 5;
  const float* er = enn + bb*1024;
  const float* br = bic + bb*1024;
  const float* wr = W_fuse + (size_t)m*2048;
  float a = 0;
  for (int jj=0;jj<1024;jj+=4){
    float4 e4 = *(const float4*)&er[jj];
    float4 w4 = *(const float4*)&wr[jj];
    a=fmaf(e4.x,w4.x,a); a=fmaf(e4.y,w4.y,a); a=fmaf(e4.z,w4.z,a); a=fmaf(e4.w,w4.w,a);
  }
  for (int jj=0;jj<1024;jj+=4){
    float4 b4 = *(const float4*)&br[jj];
    float4 w4 = *(const float4*)&wr[1024+jj];
    a=fmaf(b4.x,w4.x,a); a=fmaf(b4.y,w4.y,a); a=fmaf(b4.z,w4.z,a); a=fmaf(b4.w,w4.w,a);
  }
  fused[bb*1024 + m] = a + b_fuse[m];
}

// ---------------- K10: output = fused@W_proj.T + b_proj
__global__ __launch_bounds__(256) void k10_proj(const float* __restrict__ fused,
  const float* __restrict__ W_proj, const float* __restrict__ b_proj, float* __restrict__ outp)
{
  int gt = blockIdx.x*256 + threadIdx.x;
  int bb = gt & 31, m = gt >> 5;
  const float* fr = fused + bb*1024;
  const float* wr = W_proj + (size_t)m*1024;
  float a = 0;
  for (int jj=0;jj<1024;jj+=4){
    float4 f4 = *(const float4*)&fr[jj];
    float4 w4 = *(const float4*)&wr[jj];
    a=fmaf(f4.x,w4.x,a); a=fmaf(f4.y,w4.y,a); a=fmaf(f4.z,w4.z,a); a=fmaf(f4.w,w4.w,a);
  }
  outp[bb*1024 + m] = a + b_proj[m];
}

extern "C" void kernel_launch(void* const* d_in, const int* in_sizes, int n_in,
                              void* d_out, int out_size, void* d_ws, size_t ws_size,
                              hipStream_t stream)
{
  const float* x       = (const float*)d_in[0];
  const float* noise   = (const float*)d_in[1];
  const float* W_emb   = (const float*)d_in[2];
  const float* b_emb   = (const float*)d_in[3];
  const float* w_ih    = (const float*)d_in[4];
  const float* w_hh    = (const float*)d_in[5];
  const float* b_ih    = (const float*)d_in[6];
  const float* b_hh    = (const float*)d_in[7];
  const float* w_in    = (const float*)d_in[8];
  const float* b_in    = (const float*)d_in[9];
  const float* w_out   = (const float*)d_in[10];
  const float* b_out   = (const float*)d_in[11];
  const float* W_fix   = (const float*)d_in[12];
  const float* W_inp   = (const float*)d_in[13];
  const float* b_inp   = (const float*)d_in[14];
  const float* conv_w  = (const float*)d_in[15];
  const float* conv_b  = (const float*)d_in[16];
  const float* W_bout  = (const float*)d_in[17];
  const float* b_bout  = (const float*)d_in[18];
  const float* decay   = (const float*)d_in[19];
  const float* W_fuse  = (const float*)d_in[20];
  const float* b_fuse  = (const float*)d_in[21];
  const float* W_proj  = (const float*)d_in[22];
  const float* b_proj  = (const float*)d_in[23];

  float* out       = (float*)d_out;
  float* enn_out   = out + 32768;
  float* bicep_out = out + 65536;
  float* attn_out  = out + 98304;

  float* ws    = (float*)d_ws;
  float* fb    = ws;                    // 32000
  float* ns    = ws + 32000;            // 2,048,000 f32
  unsigned short* preh  = (unsigned short*)(ws + 2080000);   // 8,192,000 u16
  float* psum  = ws + 6200000;          // 16384
  unsigned short* lstmT = (unsigned short*)(ws + 10272000);  // 2,048,000 u16
  float* ctx   = ws + 12320000;         // 2,097,152
  float* S0    = ws + 14417152;         // 32000
  float* S1    = ws + 14449152;
  float* S2    = ws + 14481152;
  float* agg   = ws + 14513152;
  float* fused = ws + 14545152;         // 32768
  unsigned short* Qb = (unsigned short*)(ws + 14577920);  // 2,097,152 u16 each
  unsigned short* Kb = Qb + 2097152;
  unsigned short* Vt = Kb + 2097152;

  k1_emb<<<1016, 256, 0, stream>>>(x, W_emb, b_emb, W_inp, b_inp, ns, fb);
  k2_pre<<<500, 256, 0, stream>>>(ns, w_ih, b_ih, b_hh, preh);
  k3_lstm_sde<<<133, 256, 0, stream>>>(preh, lstmT, w_hh, noise, fb, conv_w, decay, S0, S1, S2);
  k4_qkv<<<256, 256, 0, stream>>>(lstmT, w_in, b_in, Qb, Kb, Vt);
  k5_attn<<<dim3(32,16), 256, 0, stream>>>(Qb, Kb, Vt, attn_out, ctx);
  k67_psum_agg<<<382, 256, 0, stream>>>(ctx, psum, S0, S1, S2, conv_b, agg);
  k68_enn_bicep<<<160, 256, 0, stream>>>(psum, w_out, b_out, W_fix, enn_out,
                                         agg, W_bout, b_bout, bicep_out);
  k9_fuse<<<128, 256, 0, stream>>>(enn_out, bicep_out, W_fuse, b_fuse, fused);
  k10_proj<<<128, 256, 0, stream>>>(fused, W_proj, b_proj, out);
}

// Round 12
// 806.807 us; speedup vs baseline: 1.1387x; 1.0217x over previous
//
#include <hip/hip_runtime.h>
#include <hip/hip_bf16.h>
#include <math.h>

#define BATCH 32

typedef short bf16x8 __attribute__((ext_vector_type(8)));
typedef float f32x4 __attribute__((ext_vector_type(4)));

__device__ __forceinline__ float sigmoidf_(float x){ return 1.0f/(1.0f + __expf(-x)); }
__device__ __forceinline__ unsigned short f2bf(float x){
  unsigned u = __float_as_uint(x);
  unsigned r = (u + 0x7FFFu + ((u>>16)&1u)) >> 16;
  return (unsigned short)r;
}
__device__ __forceinline__ float sig2(float x){
  return __builtin_amdgcn_rcpf(1.0f + __builtin_amdgcn_exp2f(x * -1.44269504f));
}
__device__ __forceinline__ float tanh2(float x){
  return 1.0f - 2.0f*__builtin_amdgcn_rcpf(1.0f + __builtin_amdgcn_exp2f(x * 2.88539008f));
}
__device__ __forceinline__ f32x4 unpk4(uint2 p){
  f32x4 r;
  r[0] = __uint_as_float(p.x << 16);
  r[1] = __uint_as_float(p.x & 0xffff0000u);
  r[2] = __uint_as_float(p.y << 16);
  r[3] = __uint_as_float(p.y & 0xffff0000u);
  return r;
}
__device__ __forceinline__ bf16x8 pack8(float4 a, float4 b){
  bf16x8 f;
  f[0]=(short)f2bf(a.x); f[1]=(short)f2bf(a.y); f[2]=(short)f2bf(a.z); f[3]=(short)f2bf(a.w);
  f[4]=(short)f2bf(b.x); f[5]=(short)f2bf(b.y); f[6]=(short)f2bf(b.z); f[7]=(short)f2bf(b.w);
  return f;
}

// ---------------- K1 v3: MFMA streaming GEMM with LDS-bf16 x.
__global__ __launch_bounds__(256) void k1_emb(const float* __restrict__ x,
    const float* __restrict__ W_emb, const float* __restrict__ b_emb,
    const float* __restrict__ W_inp, const float* __restrict__ b_inp,
    float* __restrict__ ns, float* __restrict__ fb)
{
  __shared__ __align__(16) unsigned short xb[32768];   // 64 KB
  const int tid = threadIdx.x;
  for (int i = tid; i < 4096; i += 256){
    int row = i >> 7, kblk = i & 127;
    const float* src = x + row*1024 + kblk*8;
    float4 a = *(const float4*)src;
    float4 b = *(const float4*)(src+4);
    *(bf16x8*)&xb[(kblk*32 + row)*8] = pack8(a, b);
  }
  __syncthreads();
  const int w = tid >> 6, lane = tid & 63;
  const int nl = lane & 15, g = lane >> 4;
  const int blk = blockIdx.x;
  const bool isemb = (blk < 1000);
  const int j0 = (isemb ? blk : (blk - 1000))*64 + w*16;
  const int arow = j0 + nl;
  const float* wrow = isemb ? (W_emb + (size_t)arow*1024)
                            : (W_inp + (size_t)(arow > 999 ? 999 : arow)*1024);
  f32x4 D0, D1;
  #pragma unroll
  for (int q=0;q<4;q++){
    int jr = j0 + 4*g + q;
    float bb = isemb ? b_emb[jr] : b_inp[jr > 999 ? 999 : jr];
    D0[q] = bb; D1[q] = bb;
  }
  float4 wa[2][8];
  #pragma unroll
  for (int s=0;s<4;s++){
    const float* p = wrow + s*32 + 8*g;
    wa[0][2*s]   = *(const float4*)p;
    wa[0][2*s+1] = *(const float4*)(p+4);
  }
  for (int kc=0; kc<8; kc++){
    const int cur = kc & 1;
    if (kc < 7){
      #pragma unroll
      for (int s=0;s<4;s++){
        const float* p = wrow + (kc+1)*128 + s*32 + 8*g;
        wa[cur^1][2*s]   = *(const float4*)p;
        wa[cur^1][2*s+1] = *(const float4*)(p+4);
      }
    }
    #pragma unroll
    for (int s=0;s<4;s++){
      const int kblk = kc*16 + s*4 + g;
      bf16x8 A  = pack8(wa[cur][2*s], wa[cur][2*s+1]);
      bf16x8 B0 = *(const bf16x8*)&xb[(kblk*32 + nl)*8];
      bf16x8 B1 = *(const bf16x8*)&xb[(kblk*32 + nl + 16)*8];
      D0 = __builtin_amdgcn_mfma_f32_16x16x32_bf16(A, B0, D0, 0,0,0);
      D1 = __builtin_amdgcn_mfma_f32_16x16x32_bf16(A, B1, D1, 0,0,0);
    }
  }
  if (isemb){
    *(f32x4*)&ns[(size_t)nl*64000 + j0 + 4*g] = D0;
    *(f32x4*)&ns[(size_t)(nl+16)*64000 + j0 + 4*g] = D1;
  } else {
    #pragma unroll
    for (int q=0;q<4;q++){
      int jr = j0 + 4*g + q;
      if (jr < 1000){
        fb[nl*1000 + jr]      = sig2(D0[q]);
        fb[(nl+16)*1000 + jr] = sig2(D1[q]);
      }
    }
  }
}

// ---------------- K2: preh[rn][perm(j)] = bf16( ns[rn,:]@w_ih[j,:] + b_ih[j] + b_hh[j] )
__global__ __launch_bounds__(256) void k2_pre(const float* __restrict__ ns,
   const float* __restrict__ w_ih, const float* __restrict__ b_ih, const float* __restrict__ b_hh,
   unsigned short* __restrict__ preh)
{
  __shared__ __align__(16) float nsl[64*64];   // 16KB
  const int tid = threadIdx.x;
  const int j = tid;                 // original gate-row 0..255 (gate = j>>6, jl = j&63)
  const int rn0 = blockIdx.x * 64;
  const int pcol = (j & 63)*4 + (j >> 6);
  float wreg[64];
  const float* wr = w_ih + j*64;
  #pragma unroll
  for (int k=0;k<64;k+=4){
    float4 v = *(const float4*)&wr[k];
    wreg[k]=v.x; wreg[k+1]=v.y; wreg[k+2]=v.z; wreg[k+3]=v.w;
  }
  float bias = b_ih[j] + b_hh[j];
  const float4* src = (const float4*)(ns + (size_t)rn0*64);
  for (int i=tid; i<64*16; i+=256) ((float4*)nsl)[i] = src[i];
  __syncthreads();
  for (int r=0;r<64;r++){
    float a0=0,a1=0,a2=0,a3=0;
    #pragma unroll
    for (int k=0;k<64;k+=4){
      float4 nv = *(const float4*)&nsl[r*64+k];
      a0=fmaf(nv.x,wreg[k],a0);   a1=fmaf(nv.y,wreg[k+1],a1);
      a2=fmaf(nv.z,wreg[k+2],a2); a3=fmaf(nv.w,wreg[k+3],a3);
    }
    preh[(size_t)(rn0+r)*256 + pcol] = f2bf((a0+a1)+(a2+a3) + bias);
  }
}

// ---------------- K3: r9 chained-MFMA LSTM + DEPTH-8 preh prefetch (P[u], static idx).
// blocks 0..7 = MFMA LSTM (256 thr, 4 waves, 4 batches); blocks 8..132 = SDE+conv.
__global__ __launch_bounds__(256) void k3_lstm_sde(
  const unsigned short* __restrict__ preh, unsigned short* __restrict__ lstmT,
  const float* __restrict__ w_hh,
  const float* __restrict__ noise, const float* __restrict__ fb,
  const float* __restrict__ conv_w, const float* __restrict__ decay_p,
  float* __restrict__ S0, float* __restrict__ S1, float* __restrict__ S2)
{
  __shared__ __align__(16) unsigned char shraw[8192];
  const int tid = threadIdx.x;
  if (blockIdx.x < 8){
    unsigned short* hls = (unsigned short*)shraw;   // [2][4][80] bf16 = 640 shorts
    const int b0 = blockIdx.x * 4;
    const int w = tid >> 6;          // wave 0..3
    const int lane = tid & 63;
    const int nl = lane & 15;
    const int g  = lane >> 4;        // 0..3
    const int r  = nl & 3;           // batch-local row
    for (int i = tid; i < 640; i += 256) hls[i] = 0;
    bf16x8 A[4][2];
    #pragma unroll
    for (int tt=0; tt<4; tt++){
      const int rt = 4*w + tt;
      const float* wsrc = w_hh + (size_t)((nl&3)*64 + 4*rt + (nl>>2))*64;
      #pragma unroll
      for (int kh=0; kh<2; kh++){
        bf16x8 f;
        #pragma unroll
        for (int i=0;i<8;i++) f[i] = (short)f2bf(wsrc[kh*32 + 8*g + i]);
        A[tt][kh] = f;
      }
    }
    const int jg = 16*w + 4*(nl>>2) + g;
    const int bat = b0 + r;
    const unsigned short* pp = preh + (size_t)bat*256000 + jg*4;
    uint2 P[8];
    #pragma unroll
    for (int s=0;s<8;s++) P[s] = *(const uint2*)(pp + (size_t)s*256);
    const int rdA = r*80 + (g ^ r)*8;
    const int wr = r*80 + ((jg>>3) ^ r)*8 + (jg & 7);
    unsigned short* lt = lstmT + ((size_t)bat*64 + jg)*1000;
    const bool s1 = (nl & 4) != 0, s2 = (nl & 8) != 0;
    float c = 0.f;
    unsigned ph[4];
    __syncthreads();
    int buf = 0;
    for (int tb=0; tb<1000; tb+=8){
      #pragma unroll
      for (int u=0;u<8;u++){
        bf16x8 B0 = *(const bf16x8*)&hls[buf*320 + rdA];
        bf16x8 B1 = *(const bf16x8*)&hls[buf*320 + rdA + 32];
        f32x4 Cp = unpk4(P[u]);
        int tp = tb + u + 8; if (tp > 999) tp = 999;
        P[u] = *(const uint2*)(pp + (size_t)tp*256);
        f32x4 D0 = __builtin_amdgcn_mfma_f32_16x16x32_bf16(A[0][0], B0, Cp, 0,0,0);
        D0 = __builtin_amdgcn_mfma_f32_16x16x32_bf16(A[0][1], B1, D0, 0,0,0);
        f32x4 D1 = __builtin_amdgcn_mfma_f32_16x16x32_bf16(A[1][0], B0, Cp, 0,0,0);
        D1 = __builtin_amdgcn_mfma_f32_16x16x32_bf16(A[1][1], B1, D1, 0,0,0);
        f32x4 D2 = __builtin_amdgcn_mfma_f32_16x16x32_bf16(A[2][0], B0, Cp, 0,0,0);
        D2 = __builtin_amdgcn_mfma_f32_16x16x32_bf16(A[2][1], B1, D2, 0,0,0);
        f32x4 D3 = __builtin_amdgcn_mfma_f32_16x16x32_bf16(A[3][0], B0, Cp, 0,0,0);
        D3 = __builtin_amdgcn_mfma_f32_16x16x32_bf16(A[3][1], B1, D3, 0,0,0);
        float g0 = s2 ? (s1 ? D3[0] : D2[0]) : (s1 ? D1[0] : D0[0]);
        float g1 = s2 ? (s1 ? D3[1] : D2[1]) : (s1 ? D1[1] : D0[1]);
        float g2 = s2 ? (s1 ? D3[2] : D2[2]) : (s1 ? D1[2] : D0[2]);
        float g3 = s2 ? (s1 ? D3[3] : D2[3]) : (s1 ? D1[3] : D0[3]);
        float iv = sig2(g0), fv = sig2(g1), gv = tanh2(g2), ov = sig2(g3);
        c = fv*c + iv*gv;
        float h = ov * tanh2(c);
        unsigned hb = f2bf(h);
        if (u & 1) ph[u>>1] |= hb << 16; else ph[u>>1] = hb;
        hls[(buf^1)*320 + wr] = (unsigned short)hb;
        asm volatile("s_waitcnt lgkmcnt(0)" ::: "memory");
        __builtin_amdgcn_s_barrier();
        asm volatile("" ::: "memory");
        buf ^= 1;
      }
      *(uint4*)(lt + tb) = make_uint4(ph[0], ph[1], ph[2], ph[3]);
    }
  } else {
    float* cw = (float*)shraw;        // 641*3 = 1923 floats
    for (int f = tid; f < 641*3; f += 256) cw[f] = conv_w[f];
    __syncthreads();
    int idx = (blockIdx.x - 8)*256 + tid;   // < 32000
    if (idx < 32000){
      int b = idx / 1000, n = idx - b*1000;
      float fcoef = fb[b*1000 + (n/100)];
      float dr = decay_p[0];
      const float dt = 1.0f/640.0f;
      float adec = 1.0f - dr*dt;
      float g = fcoef * sqrtf(dt);
      const float* nptr = noise + (size_t)idx * 640;
      float X=0.f, s0=0.f, s1=0.f, s2=0.f;
      for (int t0=0;t0<640;t0+=4){
        float4 nz = *(const float4*)&nptr[t0];
        float nv[4] = {nz.x, nz.y, nz.z, nz.w};
        #pragma unroll
        for (int u=0;u<4;u++){
          X = fmaf(adec, X, g*nv[u]);
          int t = t0 + u + 1;
          s0 = fmaf(cw[t*3+0], X, s0);
          s1 = fmaf(cw[t*3+1], X, s1);
          s2 = fmaf(cw[t*3+2], X, s2);
        }
      }
      S0[idx]=s0; S1[idx]=s1; S2[idx]=s2;
    }
  }
}

// ---------------- K4: qkv projection. lstm history is transposed bf16 [b][j][t].
__global__ __launch_bounds__(256) void k4_qkv(const unsigned short* __restrict__ lstmT,
  const float* __restrict__ w_in, const float* __restrict__ b_in,
  unsigned short* __restrict__ Qb, unsigned short* __restrict__ Kb, unsigned short* __restrict__ Vt)
{
  __shared__ __align__(16) float wl[192*64];   // 48KB
  __shared__ float bl[192];
  const int tid = threadIdx.x;
  for (int i=tid;i<3072;i+=256) ((float4*)wl)[i] = ((const float4*)w_in)[i];
  if (tid < 192) bl[tid] = b_in[tid];
  __syncthreads();
  const int rl = tid & 127, dh = tid >> 7;
  const int rn = blockIdx.x*128 + rl;
  const int b = rn >> 10, n = rn & 1023;
  const bool valid = (n < 1000);
  const int nc = valid ? n : 999;
  float row[64];
  #pragma unroll
  for (int k=0;k<64;k++){
    unsigned v = lstmT[((size_t)b*64 + k)*1000 + nc];
    row[k] = valid ? __uint_as_float(v << 16) : 0.f;
  }
  for (int dc=0; dc<12; dc++){
    const int d0 = dh*96 + dc*8;
    float acc[8];
    #pragma unroll
    for (int u=0;u<8;u++) acc[u] = bl[d0+u];
    #pragma unroll
    for (int k=0;k<64;k+=4){
      float4 rv = *(const float4*)&row[k];
      #pragma unroll
      for (int u=0;u<8;u++){
        float4 wv = *(const float4*)&wl[(d0+u)*64 + k];
        acc[u]=fmaf(rv.x,wv.x,acc[u]); acc[u]=fmaf(rv.y,wv.y,acc[u]);
        acc[u]=fmaf(rv.z,wv.z,acc[u]); acc[u]=fmaf(rv.w,wv.w,acc[u]);
      }
    }
    unsigned short pk[8];
    #pragma unroll
    for (int u=0;u<8;u++) pk[u] = valid ? f2bf(acc[u]) : (unsigned short)0;
    if (d0 + 8 <= 64){
      *(bf16x8*)&Qb[(size_t)rn*64 + d0] = *(bf16x8*)pk;
    } else if (d0 + 8 <= 128){
      *(bf16x8*)&Kb[(size_t)rn*64 + (d0-64)] = *(bf16x8*)pk;
    } else {
      int dv = d0 - 128;
      #pragma unroll
      for (int u=0;u<8;u++) Vt[((size_t)b*64 + dv+u)*1024 + n] = pk[u];
    }
  }
}

// ---------------- K5: attention (r10 paired form — measured better tail).
__global__ __launch_bounds__(256) void k5_attn(
  const unsigned short* __restrict__ Qb, const unsigned short* __restrict__ Kb,
  const unsigned short* __restrict__ Vt,
  float* __restrict__ attn_w, float* __restrict__ ctx)
{
  const int b = blockIdx.x;
  const int qblk = blockIdx.y;
  const int wid = threadIdx.x >> 6;
  const int lane = threadIdx.x & 63;
  const int r = lane & 15, gq = lane >> 4;
  const int q = qblk*64 + wid*16 + r;
  const bool gok = (gq < 2);
  const float SC2 = 0.25f * 1.44269504f;
  const f32x4 z4 = {0.f,0.f,0.f,0.f};

  bf16x8 qf[4];
  #pragma unroll
  for (int h=0; h<4; h++){
    bf16x8 f = {};
    if (gok) f = *(const bf16x8*)&Qb[(((size_t)b*1024)+q)*64 + h*16 + 8*gq];
    qf[h] = f;
  }
  float snv[4];
  #pragma unroll
  for (int h=0; h<4; h++){
    float es = 0.f;
    for (int kk=0; kk<63; kk++){
      bf16x8 kf = {};
      if (gok) kf = *(const bf16x8*)&Kb[(((size_t)b*1024)+(kk*16+r))*64 + h*16 + 8*gq];
      f32x4 d = __builtin_amdgcn_mfma_f32_16x16x32_bf16(kf, qf[h], z4, 0,0,0);
      float e0=__builtin_amdgcn_exp2f(d[0]*SC2), e1=__builtin_amdgcn_exp2f(d[1]*SC2);
      float e2=__builtin_amdgcn_exp2f(d[2]*SC2), e3=__builtin_amdgcn_exp2f(d[3]*SC2);
      if (kk == 62 && !gok){ e0=0;e1=0;e2=0;e3=0; }
      es += (e0+e1)+(e2+e3);
    }
    es += __shfl_xor(es, 16);
    es += __shfl_xor(es, 32);
    snv[h] = 0.25f / es;
  }
  f32x4 cacc[4] = {};
  float* awrow = attn_w + (size_t)b*1000000;
  for (int kkp=0; kkp<31; kkp++){
    const int kk = kkp*2;
    f32x4 aacc0 = z4, aacc1 = z4;
    #pragma unroll
    for (int h=0; h<4; h++){
      bf16x8 kf0 = {}, kf1 = {};
      if (gok){
        kf0 = *(const bf16x8*)&Kb[(((size_t)b*1024)+(kk*16+r))*64 + h*16 + 8*gq];
        kf1 = *(const bf16x8*)&Kb[(((size_t)b*1024)+(kk*16+16+r))*64 + h*16 + 8*gq];
      }
      f32x4 d0 = __builtin_amdgcn_mfma_f32_16x16x32_bf16(kf0, qf[h], z4, 0,0,0);
      f32x4 d1 = __builtin_amdgcn_mfma_f32_16x16x32_bf16(kf1, qf[h], z4, 0,0,0);
      float p00=__builtin_amdgcn_exp2f(d0[0]*SC2)*snv[h], p01=__builtin_amdgcn_exp2f(d0[1]*SC2)*snv[h];
      float p02=__builtin_amdgcn_exp2f(d0[2]*SC2)*snv[h], p03=__builtin_amdgcn_exp2f(d0[3]*SC2)*snv[h];
      float p10=__builtin_amdgcn_exp2f(d1[0]*SC2)*snv[h], p11=__builtin_amdgcn_exp2f(d1[1]*SC2)*snv[h];
      float p12=__builtin_amdgcn_exp2f(d1[2]*SC2)*snv[h], p13=__builtin_amdgcn_exp2f(d1[3]*SC2)*snv[h];
      aacc0[0]+=p00; aacc0[1]+=p01; aacc0[2]+=p02; aacc0[3]+=p03;
      aacc1[0]+=p10; aacc1[1]+=p11; aacc1[2]+=p12; aacc1[3]+=p13;
      const int slo = (r + 32*gq) & 63;
      const int shi = (slo + 16) & 63;
      {
        unsigned pa = (unsigned)f2bf(p00) | ((unsigned)f2bf(p01) << 16);
        unsigned pb = (unsigned)f2bf(p02) | ((unsigned)f2bf(p03) << 16);
        int b0_ = __shfl((int)pa, slo), b1_ = __shfl((int)pb, slo);
        int b2_ = __shfl((int)pa, shi), b3_ = __shfl((int)pb, shi);
        union { int i[4]; bf16x8 v; } pu;
        pu.i[0]=b0_; pu.i[1]=b1_; pu.i[2]=b2_; pu.i[3]=b3_;
        bf16x8 pfrag = pu.v;
        if (!gok) pfrag = (bf16x8){};
        bf16x8 vf = {};
        if (gok) vf = *(const bf16x8*)&Vt[(((size_t)b*64) + h*16 + r)*1024 + kk*16 + 8*gq];
        cacc[h] = __builtin_amdgcn_mfma_f32_16x16x32_bf16(vf, pfrag, cacc[h], 0,0,0);
      }
      {
        unsigned pa = (unsigned)f2bf(p10) | ((unsigned)f2bf(p11) << 16);
        unsigned pb = (unsigned)f2bf(p12) | ((unsigned)f2bf(p13) << 16);
        int b0_ = __shfl((int)pa, slo), b1_ = __shfl((int)pb, slo);
        int b2_ = __shfl((int)pa, shi), b3_ = __shfl((int)pb, shi);
        union { int i[4]; bf16x8 v; } pu;
        pu.i[0]=b0_; pu.i[1]=b1_; pu.i[2]=b2_; pu.i[3]=b3_;
        bf16x8 pfrag = pu.v;
        if (!gok) pfrag = (bf16x8){};
        bf16x8 vf = {};
        if (gok) vf = *(const bf16x8*)&Vt[(((size_t)b*64) + h*16 + r)*1024 + kk*16 + 16 + 8*gq];
        cacc[h] = __builtin_amdgcn_mfma_f32_16x16x32_bf16(vf, pfrag, cacc[h], 0,0,0);
      }
    }
    if (q < 1000){
      *(f32x4*)&awrow[(size_t)q*1000 + kk*16 + 4*gq] = aacc0;
      *(f32x4*)&awrow[(size_t)q*1000 + kk*16 + 16 + 4*gq] = aacc1;
    }
  }
  {
    const int kk = 62;
    f32x4 aacc = z4;
    #pragma unroll
    for (int h=0; h<4; h++){
      bf16x8 kf = {};
      if (gok) kf = *(const bf16x8*)&Kb[(((size_t)b*1024)+(kk*16+r))*64 + h*16 + 8*gq];
      f32x4 d = __builtin_amdgcn_mfma_f32_16x16x32_bf16(kf, qf[h], z4, 0,0,0);
      float p0=__builtin_amdgcn_exp2f(d[0]*SC2)*snv[h], p1=__builtin_amdgcn_exp2f(d[1]*SC2)*snv[h];
      float p2=__builtin_amdgcn_exp2f(d[2]*SC2)*snv[h], p3=__builtin_amdgcn_exp2f(d[3]*SC2)*snv[h];
      if (!gok){ p0=0;p1=0;p2=0;p3=0; }
      aacc[0]+=p0; aacc[1]+=p1; aacc[2]+=p2; aacc[3]+=p3;
      unsigned pa = (unsigned)f2bf(p0) | ((unsigned)f2bf(p1) << 16);
      unsigned pb = (unsigned)f2bf(p2) | ((unsigned)f2bf(p3) << 16);
      int slo = (r + 32*gq) & 63;
      int shi = (slo + 16) & 63;
      int b0_ = __shfl((int)pa, slo), b1_ = __shfl((int)pb, slo);
      int b2_ = __shfl((int)pa, shi), b3_ = __shfl((int)pb, shi);
      union { int i[4]; bf16x8 v; } pu;
      pu.i[0]=b0_; pu.i[1]=b1_; pu.i[2]=b2_; pu.i[3]=b3_;
      bf16x8 pfrag = pu.v;
      if (!gok) pfrag = (bf16x8){};
      bf16x8 vf = {};
      if (gok) vf = *(const bf16x8*)&Vt[(((size_t)b*64) + h*16 + r)*1024 + kk*16 + 8*gq];
      cacc[h] = __builtin_amdgcn_mfma_f32_16x16x32_bf16(vf, pfrag, cacc[h], 0,0,0);
    }
    if (q < 1000 && gok){
      *(f32x4*)&awrow[(size_t)q*1000 + kk*16 + 4*gq] = aacc;
    }
  }
  if (q < 1000){
    #pragma unroll
    for (int h=0; h<4; h++){
      f32x4 cv = cacc[h];
      cv[0]*=4.f; cv[1]*=4.f; cv[2]*=4.f; cv[3]*=4.f;
      *(f32x4*)&ctx[(((size_t)b*1024)+q)*64 + h*16 + 4*gq] = cv;
    }
  }
}

// ---------------- K67: blocks 0..255 = ctx partial column sums; 256..381 = agg
__global__ __launch_bounds__(256) void k67_psum_agg(const float* __restrict__ ctx,
  float* __restrict__ psum,
  const float* __restrict__ S0, const float* __restrict__ S1,
  const float* __restrict__ S2, const float* __restrict__ conv_b, float* __restrict__ agg)
{
  if (blockIdx.x < 256){
    __shared__ float part[256];
    const int blk = blockIdx.x;
    const int b = blk >> 3, seg = blk & 7;
    const int t = threadIdx.x, d = t & 63, sg = t >> 6;
    float s = 0.f;
    const int nend = seg*125 + 125;
    for (int n = seg*125 + sg; n < nend; n += 4)
      s += ctx[(((size_t)b*1024)+n)*64 + d];
    part[t] = s;
    __syncthreads();
    if (t < 64) psum[((size_t)b*8 + seg)*64 + t] = part[t] + part[64+t] + part[128+t] + part[192+t];
  } else {
    int i = (blockIdx.x - 256)*256 + threadIdx.x;
    if (i >= 32000) return;
    int n = i % 1000;
    float v = S1[i] + conv_b[0];
    if (n > 0)   v += S0[i-1];
    if (n < 999) v += S2[i+1];
    agg[i] = v;
  }
}

// ---------------- K68: blocks 0..31 = enn (psum -> relu -> W_fix); 32..159 = bicep
__global__ __launch_bounds__(256) void k68_enn_bicep(const float* __restrict__ psum,
  const float* __restrict__ w_out, const float* __restrict__ b_out,
  const float* __restrict__ W_fix, float* __restrict__ enn_out,
  const float* __restrict__ agg, const float* __restrict__ W_bout,
  const float* __restrict__ b_bout, float* __restrict__ bicep)
{
  if (blockIdx.x < 32){
    __shared__ __align__(16) float csum[64];
    __shared__ __align__(16) float epre[64];
    int b = blockIdx.x, t = threadIdx.x;
    if (t < 64){
      float a = 0;
      #pragma unroll
      for (int s2=0;s2<8;s2++) a += psum[((size_t)b*8 + s2)*64 + t];
      csum[t] = a;
    }
    __syncthreads();
    if (t < 64){
      const float* wr = w_out + t*64;
      float a = 0;
      #pragma unroll
      for (int k=0;k<64;k++) a = fmaf(csum[k], wr[k], a);
      epre[t] = fmaxf(a*(1.0f/1000.0f) + b_out[t], 0.0f);
    }
    __syncthreads();
    for (int m = t; m < 1024; m += 256){
      const float* fr = W_fix + m*64;
      float a = 0;
      #pragma unroll
      for (int k=0;k<64;k+=4){
        float4 e4 = *(const float4*)&epre[k];
        float4 f4 = *(const float4*)&fr[k];
        a=fmaf(e4.x,f4.x,a); a=fmaf(e4.y,f4.y,a); a=fmaf(e4.z,f4.z,a); a=fmaf(e4.w,f4.w,a);
      }
      enn_out[b*1024 + m] = a;
    }
  } else {
    int gt = (blockIdx.x - 32)*256 + threadIdx.x;
    int bb = gt & 31, m = gt >> 5;
    const float* wr = W_bout + (size_t)m*1000;
    const float* ar = agg + bb*1000;
    float a = 0;
    for (int n=0;n<1000;n+=4){
      float4 w4 = *(const float4*)&wr[n];
      float4 a4 = *(const float4*)&ar[n];
      a=fmaf(w4.x,a4.x,a); a=fmaf(w4.y,a4.y,a); a=fmaf(w4.z,a4.z,a); a=fmaf(w4.w,a4.w,a);
    }
    bicep[bb*1024 + m] = a + b_bout[m];
  }
}

// ---------------- K9: fused = [enn,bicep]@W_fuse.T + b_fuse
__global__ __launch_bounds__(256) void k9_fuse(const float* __restrict__ enn, const float* __restrict__ bic,
  const float* __restrict__ W_fuse, const float* __restrict__ b_fuse, float* __restrict__ fused)
{
  int gt = blockIdx.x*256 + threadIdx.x;
  int bb = gt & 31, m = gt >> 5;
  const float* er = enn + bb*1024;
  const float* br = bic + bb*1024;
  const float* wr = W_fuse + (size_t)m*2048;
  float a = 0;
  for (int jj=0;jj<1024;jj+=4){
    float4 e4 = *(const float4*)&er[jj];
    float4 w4 = *(const float4*)&wr[jj];
    a=fmaf(e4.x,w4.x,a); a=fmaf(e4.y,w4.y,a); a=fmaf(e4.z,w4.z,a); a=fmaf(e4.w,w4.w,a);
  }
  for (int jj=0;jj<1024;jj+=4){
    float4 b4 = *(const float4*)&br[jj];
    float4 w4 = *(const float4*)&wr[1024+jj];
    a=fmaf(b4.x,w4.x,a); a=fmaf(b4.y,w4.y,a); a=fmaf(b4.z,w4.z,a); a=fmaf(b4.w,w4.w,a);
  }
  fused[bb*1024 + m] = a + b_fuse[m];
}

// ---------------- K10: output = fused@W_proj.T + b_proj
__global__ __launch_bounds__(256) void k10_proj(const float* __restrict__ fused,
  const float* __restrict__ W_proj, const float* __restrict__ b_proj, float* __restrict__ outp)
{
  int gt = blockIdx.x*256 + threadIdx.x;
  int bb = gt & 31, m = gt >> 5;
  const float* fr = fused + bb*1024;
  const float* wr = W_proj + (size_t)m*1024;
  float a = 0;
  for (int jj=0;jj<1024;jj+=4){
    float4 f4 = *(const float4*)&fr[jj];
    float4 w4 = *(const float4*)&wr[jj];
    a=fmaf(f4.x,w4.x,a); a=fmaf(f4.y,w4.y,a); a=fmaf(f4.z,w4.z,a); a=fmaf(f4.w,w4.w,a);
  }
  outp[bb*1024 + m] = a + b_proj[m];
}

extern "C" void kernel_launch(void* const* d_in, const int* in_sizes, int n_in,
                              void* d_out, int out_size, void* d_ws, size_t ws_size,
                              hipStream_t stream)
{
  const float* x       = (const float*)d_in[0];
  const float* noise   = (const float*)d_in[1];
  const float* W_emb   = (const float*)d_in[2];
  const float* b_emb   = (const float*)d_in[3];
  const float* w_ih    = (const float*)d_in[4];
  const float* w_hh    = (const float*)d_in[5];
  const float* b_ih    = (const float*)d_in[6];
  const float* b_hh    = (const float*)d_in[7];
  const float* w_in    = (const float*)d_in[8];
  const float* b_in    = (const float*)d_in[9];
  const float* w_out   = (const float*)d_in[10];
  const float* b_out   = (const float*)d_in[11];
  const float* W_fix   = (const float*)d_in[12];
  const float* W_inp   = (const float*)d_in[13];
  const float* b_inp   = (const float*)d_in[14];
  const float* conv_w  = (const float*)d_in[15];
  const float* conv_b  = (const float*)d_in[16];
  const float* W_bout  = (const float*)d_in[17];
  const float* b_bout  = (const float*)d_in[18];
  const float* decay   = (const float*)d_in[19];
  const float* W_fuse  = (const float*)d_in[20];
  const float* b_fuse  = (const float*)d_in[21];
  const float* W_proj  = (const float*)d_in[22];
  const float* b_proj  = (const float*)d_in[23];

  float* out       = (float*)d_out;
  float* enn_out   = out + 32768;
  float* bicep_out = out + 65536;
  float* attn_out  = out + 98304;

  float* ws    = (float*)d_ws;
  float* fb    = ws;                    // 32000
  float* ns    = ws + 32000;            // 2,048,000 f32
  unsigned short* preh  = (unsigned short*)(ws + 2080000);   // 8,192,000 u16
  float* psum  = ws + 6200000;          // 16384
  unsigned short* lstmT = (unsigned short*)(ws + 10272000);  // 2,048,000 u16
  float* ctx   = ws + 12320000;         // 2,097,152
  float* S0    = ws + 14417152;         // 32000
  float* S1    = ws + 14449152;
  float* S2    = ws + 14481152;
  float* agg   = ws + 14513152;
  float* fused = ws + 14545152;         // 32768
  unsigned short* Qb = (unsigned short*)(ws + 14577920);  // 2,097,152 u16 each
  unsigned short* Kb = Qb + 2097152;
  unsigned short* Vt = Kb + 2097152;

  k1_emb<<<1016, 256, 0, stream>>>(x, W_emb, b_emb, W_inp, b_inp, ns, fb);
  k2_pre<<<500, 256, 0, stream>>>(ns, w_ih, b_ih, b_hh, preh);
  k3_lstm_sde<<<133, 256, 0, stream>>>(preh, lstmT, w_hh, noise, fb, conv_w, decay, S0, S1, S2);
  k4_qkv<<<256, 256, 0, stream>>>(lstmT, w_in, b_in, Qb, Kb, Vt);
  k5_attn<<<dim3(32,16), 256, 0, stream>>>(Qb, Kb, Vt, attn_out, ctx);
  k67_psum_agg<<<382, 256, 0, stream>>>(ctx, psum, S0, S1, S2, conv_b, agg);
  k68_enn_bicep<<<160, 256, 0, stream>>>(psum, w_out, b_out, W_fix, enn_out,
                                         agg, W_bout, b_bout, bicep_out);
  k9_fuse<<<128, 256, 0, stream>>>(enn_out, bicep_out, W_fuse, b_fuse, fused);
  k10_proj<<<128, 256, 0, stream>>>(fused, W_proj, b_proj, out);
}